// Round 5
// baseline (547.229 us; speedup 1.0000x reference)
//
#include <hip/hip_runtime.h>

#define N_NODES 100000
#define N_PAD   100096      // 782 * 128
#define N_EDGES 1600000
#define NEG_SLOPE 0.2f
#define BN_EPS 1e-5f

typedef __attribute__((ext_vector_type(8))) short short8;
typedef __attribute__((ext_vector_type(4))) float floatx4;

// ---------------- workspace layout (bytes) ----------------
static const size_t OFF_AB   = 0;            // feats bf16 fragment-ordered [N_PAD,128]
static const size_t OFF_BB   = 25624576;     // weights bf16 fragment-ordered [512,128]
static const size_t OFF_H    = 25755648;     // h bf16 [N,256]
static const size_t OFF_RES  = 76955648;     // res+bias bf16 [N,256]
static const size_t OFF_EL   = 128155648;    // el [N,4] f32
static const size_t OFF_ER   = 129755648;    // er [N,4] f32
static const size_t OFF_DEG  = 131355648;    // deg [N] i32
static const size_t OFF_RS   = 131755648;    // row_start [N+1] i32
static const size_t OFF_CUR  = 132155664;    // cursor [N] i32
static const size_t OFF_ESRC = 132555664;    // edge src ids [E] i32
static const size_t OFF_BS   = 138955664;    // block sums [128] i32
static const size_t OFF_BN   = 138956176;    // bn accum [128] f32
static const size_t OFF_EW   = 138956800;    // edge weights [E,4] f32 = 25.6 MB
// total ~164.6 MB

__device__ __forceinline__ unsigned short f2bf(float x) {
  unsigned int u = __float_as_uint(x);
  unsigned int r = (u + 0x7fffu + ((u >> 16) & 1u)) >> 16;   // RNE
  return (unsigned short)r;
}
__device__ __forceinline__ float bf_lo(unsigned int u) {     // even ushort -> f32
  return __uint_as_float(u << 16);
}
__device__ __forceinline__ float bf_hi(unsigned int u) {     // odd ushort -> f32
  return __uint_as_float(u & 0xffff0000u);
}

// ---------------- fused pre-pass: cvt_a | edge count | cvt_w ----------------
__global__ __launch_bounds__(256) void k_pre(
    const float* __restrict__ feats, const float* __restrict__ fc_w,
    const float* __restrict__ res_w, const int* __restrict__ dst,
    unsigned short* __restrict__ Ab, unsigned short* __restrict__ Bb,
    int* __restrict__ deg)
{
  const int b = blockIdx.x;
  if (b < 6256) {                                // ---- cvt_a
    int c = b * 256 + threadIdx.x;
    int r = c >> 4, j = c & 15;
    unsigned short v[8];
    if (r < N_NODES) {
      const float* p = feats + (size_t)r * 128 + j * 8;
      float4 a = *(const float4*)p, bb = *(const float4*)(p + 4);
      v[0]=f2bf(a.x); v[1]=f2bf(a.y); v[2]=f2bf(a.z); v[3]=f2bf(a.w);
      v[4]=f2bf(bb.x); v[5]=f2bf(bb.y); v[6]=f2bf(bb.z); v[7]=f2bf(bb.w);
    } else {
      for (int i = 0; i < 8; i++) v[i] = 0;
    }
    size_t idx = (size_t)(r >> 7) * 2048 + ((r >> 4) & 7) * 256 + (j >> 2) * 64
               + (r & 15) + 16 * (j & 3);
    *(short8*)(Ab + idx * 8) = *(short8*)v;
  } else if (b < 12506) {                        // ---- count degrees
    int e = (b - 6256) * 256 + threadIdx.x;
    if (e < N_EDGES) atomicAdd(&deg[dst[e]], 1);
  } else {                                       // ---- cvt_w
    int c = (b - 12506) * 256 + threadIdx.x;
    int n = c >> 4, j = c & 15;
    const float* W = (n < 256) ? (fc_w + (size_t)n * 128) : (res_w + (size_t)(n - 256) * 128);
    const float* p = W + j * 8;
    float4 a = *(const float4*)p, bb = *(const float4*)(p + 4);
    unsigned short v[8];
    v[0]=f2bf(a.x); v[1]=f2bf(a.y); v[2]=f2bf(a.z); v[3]=f2bf(a.w);
    v[4]=f2bf(bb.x); v[5]=f2bf(bb.y); v[6]=f2bf(bb.z); v[7]=f2bf(bb.w);
    size_t idx = (size_t)(n >> 7) * 2048 + ((n >> 4) & 7) * 256 + (j >> 2) * 64
               + (n & 15) + 16 * (j & 3);
    *(short8*)(Bb + idx * 8) = *(short8*)v;
  }
}

// ---------------- MFMA projection + fused el/er -----------------------------
__global__ __launch_bounds__(256) void k_mm(
    const unsigned short* __restrict__ Ab, const unsigned short* __restrict__ Bb,
    const float* __restrict__ bias, const float* __restrict__ attn_l,
    const float* __restrict__ attn_r,
    unsigned short* __restrict__ hbuf, unsigned short* __restrict__ resbuf,
    float* __restrict__ el, float* __restrict__ er)
{
  __shared__ unsigned short sA[16384];  // 32 KB, fragment-ordered A block
  const int tid = threadIdx.x;
  const int w = tid >> 6, L = tid & 63;
  const int blk = blockIdx.x, nb = blockIdx.y;

  {
    const unsigned short* ga = Ab + (size_t)blk * 16384;
    #pragma unroll
    for (int i = 0; i < 8; i++) {
      int off = (i * 256 + w * 64) * 8;
      __builtin_amdgcn_global_load_lds(
          (const __attribute__((address_space(1))) unsigned int*)(ga + off + L * 8),
          (__attribute__((address_space(3))) unsigned int*)(sA + off),
          16, 0, 0);
    }
  }
  const int mh = w & 1, nh = w >> 1;
  floatx4 acc[4][4] = {};
  __syncthreads();

  const unsigned short* gb = Bb + ((size_t)nb * 2048 + nh * 4 * 256) * 8 + L * 8;
  #pragma unroll
  for (int s = 0; s < 4; s++) {
    short8 a[4], b[4];
    #pragma unroll
    for (int t = 0; t < 4; t++)
      a[t] = *(const short8*)(sA + ((mh * 4 + t) * 256 + s * 64 + L) * 8);
    #pragma unroll
    for (int t = 0; t < 4; t++)
      b[t] = *(const short8*)(gb + ((size_t)t * 256 + s * 64) * 8);
    #pragma unroll
    for (int mt = 0; mt < 4; mt++)
      #pragma unroll
      for (int nt = 0; nt < 4; nt++)
        acc[mt][nt] = __builtin_amdgcn_mfma_f32_16x16x32_bf16(a[mt], b[nt], acc[mt][nt], 0, 0, 0);
  }

  const int q = L >> 4, cn = L & 15;
  const int r0 = blk * 128 + mh * 64;
  if (nb < 2) {
    const int head = nb * 2 + nh;
    const int col0 = nb * 128 + nh * 64;
    float al[4], ar[4];
    #pragma unroll
    for (int nt = 0; nt < 4; nt++) {
      al[nt] = attn_l[head * 64 + nt * 16 + cn];
      ar[nt] = attn_r[head * 64 + nt * 16 + cn];
    }
    #pragma unroll
    for (int mt = 0; mt < 4; mt++)
      #pragma unroll
      for (int r = 0; r < 4; r++) {
        const int row = r0 + mt * 16 + q * 4 + r;
        float pl = 0.f, pr = 0.f;
        #pragma unroll
        for (int nt = 0; nt < 4; nt++) {
          pl = fmaf(acc[mt][nt][r], al[nt], pl);
          pr = fmaf(acc[mt][nt][r], ar[nt], pr);
        }
        #pragma unroll
        for (int o = 1; o < 16; o <<= 1) {
          pl += __shfl_xor(pl, o, 64);
          pr += __shfl_xor(pr, o, 64);
        }
        if (row < N_NODES) {
          #pragma unroll
          for (int nt = 0; nt < 4; nt++)
            hbuf[(size_t)row * 256 + col0 + nt * 16 + cn] = f2bf(acc[mt][nt][r]);
          if (cn == 0) {
            el[row * 4 + head] = pl;
            er[row * 4 + head] = pr;
          }
        }
      }
  } else {
    const int rc0 = (nb - 2) * 128 + nh * 64;
    #pragma unroll
    for (int mt = 0; mt < 4; mt++)
      #pragma unroll
      for (int r = 0; r < 4; r++) {
        const int row = r0 + mt * 16 + q * 4 + r;
        if (row < N_NODES)
          #pragma unroll
          for (int nt = 0; nt < 4; nt++) {
            float v = acc[mt][nt][r] + bias[rc0 + nt * 16 + cn];
            resbuf[(size_t)row * 256 + rc0 + nt * 16 + cn] = f2bf(v);
          }
      }
  }
}

// ---------------- CSR build ----------------
__global__ __launch_bounds__(256) void k_scan1(const int* __restrict__ deg,
                                               int* __restrict__ rs, int* __restrict__ bsums)
{
  __shared__ int tmp[256];
  const int t = threadIdx.x;
  const int base = blockIdx.x * 1024 + t * 4;
  int v0 = 0, v1 = 0, v2 = 0, v3 = 0;
  if (base + 0 < N_NODES) v0 = deg[base + 0];
  if (base + 1 < N_NODES) v1 = deg[base + 1];
  if (base + 2 < N_NODES) v2 = deg[base + 2];
  if (base + 3 < N_NODES) v3 = deg[base + 3];
  const int tsum = v0 + v1 + v2 + v3;
  tmp[t] = tsum;
  __syncthreads();
  for (int o = 1; o < 256; o <<= 1) {
    int x = (t >= o) ? tmp[t - o] : 0;
    __syncthreads();
    tmp[t] += x;
    __syncthreads();
  }
  const int excl = tmp[t] - tsum;
  if (base + 0 < N_NODES) rs[base + 0] = excl;
  if (base + 1 < N_NODES) rs[base + 1] = excl + v0;
  if (base + 2 < N_NODES) rs[base + 2] = excl + v0 + v1;
  if (base + 3 < N_NODES) rs[base + 3] = excl + v0 + v1 + v2;
  if (t == 255) bsums[blockIdx.x] = tmp[t];
}

__global__ __launch_bounds__(256) void k_scan3(int* __restrict__ rs,
                                               const int* __restrict__ bsums,
                                               int* __restrict__ cursor)
{
  __shared__ int sb[128];
  const int t = threadIdx.x;
  int raw = 0;
  if (t < 128) { raw = (t < 98) ? bsums[t] : 0; sb[t] = raw; }
  __syncthreads();
  for (int o = 1; o < 128; o <<= 1) {
    int x = (t >= o && t < 128) ? sb[t - o] : 0;
    __syncthreads();
    if (t < 128) sb[t] += x;
    __syncthreads();
  }
  if (t < 128) sb[t] -= raw;
  __syncthreads();
  const int i = blockIdx.x * 256 + t;
  if (i < N_NODES) {
    int v = rs[i] + sb[i >> 10];
    rs[i] = v;
    cursor[i] = v;
  } else if (i == N_NODES) {
    rs[N_NODES] = N_EDGES;
  }
}

// ---------------- scatter + edge weight precompute --------------------------
__global__ __launch_bounds__(256) void k_scatter(
    const int* __restrict__ src, const int* __restrict__ dst,
    const float* __restrict__ el, const float* __restrict__ er,
    int* __restrict__ cursor, int* __restrict__ esrc, float* __restrict__ ewgt)
{
  int e = blockIdx.x * 256 + threadIdx.x;
  if (e >= N_EDGES) return;
  const int s = src[e], d = dst[e];
  const float4 l4 = *(const float4*)(el + (size_t)s * 4);
  const float4 r4 = *(const float4*)(er + (size_t)d * 4);
  float4 w;
  float t;
  t = l4.x + r4.x; t = (t > 0.f) ? t : NEG_SLOPE * t; w.x = __expf(t);
  t = l4.y + r4.y; t = (t > 0.f) ? t : NEG_SLOPE * t; w.y = __expf(t);
  t = l4.z + r4.z; t = (t > 0.f) ? t : NEG_SLOPE * t; w.z = __expf(t);
  t = l4.w + r4.w; t = (t > 0.f) ? t : NEG_SLOPE * t; w.w = __expf(t);
  const int pos = atomicAdd(&cursor[d], 1);
  esrc[pos] = s;
  *(float4*)(ewgt + (size_t)pos * 4) = w;
}

// ---------------- fused aggregation + residual/ELU/head-mean ----------------
// one wave per dst node; 2 edges per step (half-wave each, 16 B/lane);
// distance-2 software pipeline, slots ALWAYS reloaded (clamped + W=0 mask)
__global__ __launch_bounds__(256) void k_agg(
    const unsigned short* __restrict__ hbuf, const unsigned short* __restrict__ resbuf,
    const int* __restrict__ rs, const int* __restrict__ esrc,
    const float* __restrict__ ewgt,
    float* __restrict__ out, float* __restrict__ bn)
{
  const int tid = threadIdx.x;
  const int L = tid & 63;
  const int half = L >> 5;          // which edge of the pair
  const int j = L & 31;             // 32 lanes cover 256 dims (16 B each)
  const int head = j >> 3;          // 0..3
  const int c = j & 7;              // dim group: dims head*64 + c*8 .. +7
  const int waveG = blockIdx.x * 4 + (tid >> 6);
  const int nW = gridDim.x * 4;

  float s8[8], q8[8];
  #pragma unroll
  for (int i = 0; i < 8; i++) { s8[i] = 0.f; q8[i] = 0.f; }

  for (int n = waveG; n < N_NODES; n += nW) {
    const int nu = __builtin_amdgcn_readfirstlane(n);
    const int p0 = __builtin_amdgcn_readfirstlane(rs[nu]);
    const int p1 = __builtin_amdgcn_readfirstlane(rs[nu + 1]);
    float acc[8];
    #pragma unroll
    for (int i = 0; i < 8; i++) acc[i] = 0.f;
    float ssum = 0.f;

    if (p0 < p1) {
      float w0, w1;
      uint4 h0, h1;
      // every load is unconditional: invalid edges clamp to p0 and mask W=0,
      // so a consumed slot is always the slot loaded for THIS iteration
      // (conditional reloads caused stale double-consumption -> R4 FAIL)
      #define LOAD_SLOT(W, H, PP) {                                            \
        int pe = (PP) + half;                                                  \
        bool valid = pe < p1;                                                  \
        int pec = valid ? pe : p0;                                             \
        float wr = ewgt[(size_t)pec * 4 + head];                               \
        int sn = esrc[pec];                                                    \
        W = valid ? wr : 0.f;                                                  \
        H = *(const uint4*)(hbuf + (size_t)sn * 256 + j * 8);                  \
      }
      #define CONSUME(W, H) {                                                  \
        ssum += W;                                                             \
        acc[0] = fmaf(W, bf_lo(H.x), acc[0]);                                  \
        acc[1] = fmaf(W, bf_hi(H.x), acc[1]);                                  \
        acc[2] = fmaf(W, bf_lo(H.y), acc[2]);                                  \
        acc[3] = fmaf(W, bf_hi(H.y), acc[3]);                                  \
        acc[4] = fmaf(W, bf_lo(H.z), acc[4]);                                  \
        acc[5] = fmaf(W, bf_hi(H.z), acc[5]);                                  \
        acc[6] = fmaf(W, bf_lo(H.w), acc[6]);                                  \
        acc[7] = fmaf(W, bf_hi(H.w), acc[7]);                                  \
      }
      LOAD_SLOT(w0, h0, p0)
      LOAD_SLOT(w1, h1, p0 + 2)
      for (int p = p0; p < p1; p += 4) {
        CONSUME(w0, h0)
        LOAD_SLOT(w0, h0, p + 4)
        CONSUME(w1, h1)
        LOAD_SLOT(w1, h1, p + 6)
      }
      #undef LOAD_SLOT
      #undef CONSUME
    }

    // combine the two half-wave edge subsets
    #pragma unroll
    for (int i = 0; i < 8; i++) acc[i] += __shfl_xor(acc[i], 32, 64);
    ssum += __shfl_xor(ssum, 32, 64);
    const float inv = (p1 > p0) ? (1.0f / ssum) : 0.f;

    // residual (bias folded) + ELU
    const uint4 rv = *(const uint4*)(resbuf + (size_t)nu * 256 + j * 8);
    float v[8];
    v[0] = fmaf(acc[0], inv, bf_lo(rv.x));
    v[1] = fmaf(acc[1], inv, bf_hi(rv.x));
    v[2] = fmaf(acc[2], inv, bf_lo(rv.y));
    v[3] = fmaf(acc[3], inv, bf_hi(rv.y));
    v[4] = fmaf(acc[4], inv, bf_lo(rv.z));
    v[5] = fmaf(acc[5], inv, bf_hi(rv.z));
    v[6] = fmaf(acc[6], inv, bf_lo(rv.w));
    v[7] = fmaf(acc[7], inv, bf_hi(rv.w));
    #pragma unroll
    for (int i = 0; i < 8; i++)
      v[i] = (v[i] > 0.f) ? v[i] : (__expf(v[i]) - 1.f);

    // head mean: reduce over head bits (j bits 3,4), scale by 1/4
    #pragma unroll
    for (int i = 0; i < 8; i++) {
      v[i] += __shfl_xor(v[i], 8, 64);
      v[i] += __shfl_xor(v[i], 16, 64);
      v[i] *= 0.25f;
    }

    if (L < 8) {   // half 0, head 0: lanes own dims c*8..c*8+7
      *(float4*)(out + (size_t)nu * 64 + c * 8)     = make_float4(v[0], v[1], v[2], v[3]);
      *(float4*)(out + (size_t)nu * 64 + c * 8 + 4) = make_float4(v[4], v[5], v[6], v[7]);
      #pragma unroll
      for (int i = 0; i < 8; i++) {
        s8[i] += v[i];
        q8[i] += v[i] * v[i];
      }
    }
  }

  // BN partial flush
  __shared__ float lsum[64], lsq[64];
  if (tid < 64) { lsum[tid] = 0.f; lsq[tid] = 0.f; }
  __syncthreads();
  if (L < 8) {
    #pragma unroll
    for (int i = 0; i < 8; i++) {
      atomicAdd(&lsum[c * 8 + i], s8[i]);
      atomicAdd(&lsq[c * 8 + i], q8[i]);
    }
  }
  __syncthreads();
  if (tid < 64) {
    atomicAdd(&bn[tid], lsum[tid]);
    atomicAdd(&bn[64 + tid], lsq[tid]);
  }
}

// ---------------- batchnorm (stats folded in) ----------------
__global__ __launch_bounds__(256) void k_bn_apply(float* __restrict__ out,
                                                  const float* __restrict__ bn,
                                                  const float* __restrict__ gamma,
                                                  const float* __restrict__ beta)
{
  __shared__ float sc[64], sh[64];
  const int t = threadIdx.x;
  if (t < 64) {
    float mean = bn[t] * (1.0f / N_NODES);
    float var = bn[64 + t] * (1.0f / N_NODES) - mean * mean;
    float s = gamma[t] * rsqrtf(var + BN_EPS);
    sc[t] = s;
    sh[t] = beta[t] - mean * s;
  }
  __syncthreads();
  const int i = blockIdx.x * 256 + t;
  if (i >= N_NODES * 16) return;
  const int d0 = (i & 15) * 4;
  float4 v = *(float4*)(out + (size_t)i * 4);
  v.x = fmaf(v.x, sc[d0 + 0], sh[d0 + 0]);
  v.y = fmaf(v.y, sc[d0 + 1], sh[d0 + 1]);
  v.z = fmaf(v.z, sc[d0 + 2], sh[d0 + 2]);
  v.w = fmaf(v.w, sc[d0 + 3], sh[d0 + 3]);
  *(float4*)(out + (size_t)i * 4) = v;
}

extern "C" void kernel_launch(void* const* d_in, const int* in_sizes, int n_in,
                              void* d_out, int out_size, void* d_ws, size_t ws_size,
                              hipStream_t stream)
{
  const float* feats  = (const float*)d_in[0];
  const int*   src    = (const int*)d_in[1];
  const int*   dst    = (const int*)d_in[2];
  const float* fc_w   = (const float*)d_in[3];
  const float* attn_l = (const float*)d_in[4];
  const float* attn_r = (const float*)d_in[5];
  const float* res_w  = (const float*)d_in[6];
  const float* bias   = (const float*)d_in[7];
  const float* gamma  = (const float*)d_in[8];
  const float* beta   = (const float*)d_in[9];

  char* ws = (char*)d_ws;
  unsigned short* Ab     = (unsigned short*)(ws + OFF_AB);
  unsigned short* Bb     = (unsigned short*)(ws + OFF_BB);
  unsigned short* hbuf   = (unsigned short*)(ws + OFF_H);
  unsigned short* resbuf = (unsigned short*)(ws + OFF_RES);
  float* elb    = (float*)(ws + OFF_EL);
  float* erb    = (float*)(ws + OFF_ER);
  int*   deg    = (int*)(ws + OFF_DEG);
  int*   rsb    = (int*)(ws + OFF_RS);
  int*   curb   = (int*)(ws + OFF_CUR);
  int*   esrc   = (int*)(ws + OFF_ESRC);
  int*   bsums  = (int*)(ws + OFF_BS);
  float* bnb    = (float*)(ws + OFF_BN);
  float* ewgt   = (float*)(ws + OFF_EW);
  float* outp   = (float*)d_out;

  hipMemsetAsync(deg, 0, N_NODES * sizeof(int), stream);
  hipMemsetAsync(bnb, 0, 128 * sizeof(float), stream);

  k_pre<<<12538, 256, 0, stream>>>(feats, fc_w, res_w, dst, Ab, Bb, deg);
  k_mm<<<dim3(782, 4), 256, 0, stream>>>(Ab, Bb, bias, attn_l, attn_r,
                                         hbuf, resbuf, elb, erb);
  k_scan1<<<98, 256, 0, stream>>>(deg, rsb, bsums);
  k_scan3<<<391, 256, 0, stream>>>(rsb, bsums, curb);
  k_scatter<<<6250, 256, 0, stream>>>(src, dst, elb, erb, curb, esrc, ewgt);
  k_agg<<<2048, 256, 0, stream>>>(hbuf, resbuf, rsb, esrc, ewgt, outp, bnb);
  k_bn_apply<<<6250, 256, 0, stream>>>(outp, bnb, gamma, beta);
}